// Round 16
// baseline (324.337 us; speedup 1.0000x reference)
//
#include <hip/hip_runtime.h>

#define V 255
#define L 16
#define P 8
#define CLIPV 10.0f

// tanh(0.5*clip(s,-10,10)) = 1 - 2/(exp(clip)+1), then zsub (0 -> 1)
__device__ __forceinline__ float tanh_zsub(float s) {
    float t = fminf(fmaxf(s, -CLIPV), CLIPV);
    float e = __expf(t);
    float o = 1.0f - __fdividef(2.0f, e + 1.0f);
    return (o == 0.0f) ? 1.0f : o;
}

// Anti-phase dual-unit kernel: units A and B in one block, phases offset by
// half an iteration so every barrier interval mixes one unit's LDS-heavy
// gather (G) with the other unit's VALU/trans-heavy compute (C+W). Two
// register-independent streams per thread -> cross-pipe overlap within each
// interval. Fused even+odd algebra (cr(rc(i))==i), padded stride-256 LDS,
// thread 255 = live dummy (no predication in hot code).
template <int MODE>
__global__ __launch_bounds__(256, 4) void bap_kernel(
    const float* __restrict__ x,
    const float* __restrict__ oddw_v,
    const float* __restrict__ oddw_e,
    const float* __restrict__ w_e_out,
    const int*   __restrict__ perma,
    const int*   __restrict__ rc_idx,
    const int*   __restrict__ cr_idx,
    float* __restrict__ eo_ws,     // MODE 0
    const int* __restrict__ invp,  // MODE 1
    float* __restrict__ out)       // MODE 1
{
    __shared__ float OOA[L * 256];   // unit A zsub'd odd outputs, 16 KB
    __shared__ float OOB[L * 256];   // unit B, 16 KB
    __shared__ float TOTA[256];      // row totals A, 1 KB
    __shared__ float TOTB[256];      // row totals B, 1 KB

    const int tid = threadIdx.x;
    const int blk = blockIdx.x;        // pair id
    const int b  = blk >> 2;
    const int pA = (blk & 3) * 2;
    const int pB = pA + 1;
    const int v  = tid;                // 0..255; 255 = dummy (full duty)
    const int vi = (v < V) ? v : (V - 1);
    const int vc = (v < V) ? (v + 1) : V;

    float xvA, xvB;
    {
        const float* xrow = x + b * (V + 1);
        xvA = xrow[perma[pA * (V + 1) + vc]];
        xvB = xrow[perma[pB * (V + 1) + vc]];
    }

    // packed indices: lo16 = OO elem (cr-gather, stride 256), hi16 = TOT elem
    unsigned pk[L];
    {
        const int4* rc4 = (const int4*)(rc_idx + vi * L);
        const int4* cr4 = (const int4*)(cr_idx + vi * L);
#pragma unroll
        for (int i = 0; i < 4; ++i) {
            int4 a = rc4[i];
            int4 c = cr4[i];
            pk[4*i+0] = ((unsigned)(a.x >> 4) << 16) | (((c.x & 15) << 8) | (c.x >> 4));
            pk[4*i+1] = ((unsigned)(a.y >> 4) << 16) | (((c.y & 15) << 8) | (c.y >> 4));
            pk[4*i+2] = ((unsigned)(a.z >> 4) << 16) | (((c.z & 15) << 8) | (c.z >> 4));
            pk[4*i+3] = ((unsigned)(a.w >> 4) << 16) | (((c.w & 15) << 8) | (c.w >> 4));
        }
    }

    float evA[L], evB[L];

    // ---- phase macros (lambdas) ----
    auto W = [&](float* OO, float* ev) {
#pragma unroll
        for (int m = 0; m < L; ++m) OO[(m << 8) + v] = ev[m];
    };
    auto G = [&](const float* OO, float* TOT) {
        float t0 = OO[pk[0] & 0xffffu], t1 = OO[pk[1] & 0xffffu];
        float t2 = OO[pk[2] & 0xffffu], t3 = OO[pk[3] & 0xffffu];
#pragma unroll
        for (int l = 4; l < L; l += 4) {
            t0 *= OO[pk[l + 0] & 0xffffu];
            t1 *= OO[pk[l + 1] & 0xffffu];
            t2 *= OO[pk[l + 2] & 0xffffu];
            t3 *= OO[pk[l + 3] & 0xffffu];
        }
        TOT[v] = (t0 * t1) * (t2 * t3);
    };
    // logratio: r = T/e; log((1+r)/(1-r+1e-9)+1e-9) == log((e+T)/(e-T+1e-9*e))
    // to ~1e-6 (|r| <= tanh(5)^15 ~ 0.9986; t=0 clip is an identity).
    auto CLOG = [&](const float* TOT, float* ev) {
#pragma unroll
        for (int l = 0; l < L; ++l) {
            float Tl = TOT[pk[l] >> 16];
            float e  = ev[l];
            float num = e + Tl;
            float den = fmaf(e, 1e-9f, e - Tl);
            ev[l] = __logf(__fdividef(num, den));
        }
    };
    auto MATV = [&](float* ev, float xv, int tn) {
        const float* __restrict__ wv = oddw_v + tn * L;
        const float* __restrict__ wm = oddw_e + tn * (L * L);
        float s[L];
#pragma unroll
        for (int m = 0; m < L; ++m) s[m] = xv * wv[m];   // uniform s_load
#pragma unroll
        for (int l = 0; l < L; ++l) {
            const float el = ev[l];
#pragma unroll
            for (int m = 0; m < L; ++m) {
                if (m != l)                     // diag mask, compile-time
                    s[m] = fmaf(el, wm[l * L + m], s[m]);
            }
        }
#pragma unroll
        for (int m = 0; m < L; ++m) ev[m] = tanh_zsub(s[m]);
    };

    // ---- t=0 odd layer (message==0 -> rank-1), zsub'd ----
#pragma unroll
    for (int m = 0; m < L; ++m) {
        float w0 = oddw_v[m];                   // uniform s_load
        evA[m] = tanh_zsub(xvA * w0);
        evB[m] = tanh_zsub(xvB * w0);
    }

    // ---- anti-phase pipeline ----
    W(OOA, evA);
    __syncthreads();                 // b0: OOA(0) ready
    G(OOA, TOTA);  W(OOB, evB);
    __syncthreads();                 // b1: TOTA(0), OOB(0) ready

#pragma unroll
    for (int t = 0; t < 4; ++t) {
        // interval: C_A(t)+W_A(t+1)  ||  G_B(t)
        CLOG(TOTA, evA); MATV(evA, xvA, t + 1); W(OOA, evA);
        G(OOB, TOTB);
        __syncthreads();             // OOA(t+1), TOTB(t) ready
        // interval: G_A(t+1)  ||  C_B(t)+W_B(t+1)
        G(OOA, TOTA);
        CLOG(TOTB, evB); MATV(evB, xvB, t + 1); W(OOB, evB);
        __syncthreads();             // TOTA(t+1), OOB(t+1) ready
    }

    // tail: C_A(4) || G_B(4); then C_B(4)
    CLOG(TOTA, evA);
    G(OOB, TOTB);
    __syncthreads();                 // TOTB(4) ready
    CLOG(TOTB, evB);

    // ---- final: dot with w_e_out straight from registers ----
    if (v < V) {
        float dA = 0.0f, dB = 0.0f;
#pragma unroll
        for (int l = 0; l < L; ++l) {
            float w = w_e_out[l];               // uniform s_load
            dA = fmaf(evA[l], w, dA);
            dB = fmaf(evB[l], w, dB);
        }
        const int uA = blk * 2;
        if (MODE == 0) {
            eo_ws[(size_t)uA * V + v]       = dA;
            eo_ws[(size_t)(uA + 1) * V + v] = dB;
        } else {
            int ja = invp[pA * (V + 1) + (v + 1)];
            int jb = invp[pB * (V + 1) + (v + 1)];
            atomicAdd(&out[b * (V + 1) + ja], dA);
            atomicAdd(&out[b * (V + 1) + jb], dB);
        }
    }
}

// gather-sum epilogue (MODE 0 path)
__global__ __launch_bounds__(256) void out_kernel(
    const float* __restrict__ x,
    const float* __restrict__ eo_ws,
    const int* __restrict__ perma,
    float* __restrict__ out)
{
    const int b = blockIdx.x;
    const int j = threadIdx.x;   // 0..255
    float acc = x[b * (V + 1) + j];
#pragma unroll
    for (int p = 0; p < P; ++p) {
        int idx = perma[p * (V + 1) + j];
        if (idx > 0) acc += eo_ws[((size_t)(b * P + p)) * V + (idx - 1)];
    }
    out[b * (V + 1) + j] = acc;
}

// fallback helpers (MODE 1 path)
__global__ __launch_bounds__(256) void inv_kernel(const int* __restrict__ perma,
                                                  int* __restrict__ invp)
{
    int p = blockIdx.x, j = threadIdx.x;
    invp[p * (V + 1) + perma[p * (V + 1) + j]] = j;
}

__global__ __launch_bounds__(256) void copy_kernel(const float* __restrict__ x,
                                                   float* __restrict__ out, int n)
{
    int i = blockIdx.x * 256 + threadIdx.x;
    if (i < n) out[i] = x[i];
}

extern "C" void kernel_launch(void* const* d_in, const int* in_sizes, int n_in,
                              void* d_out, int out_size, void* d_ws, size_t ws_size,
                              hipStream_t stream)
{
    const float* x       = (const float*)d_in[0];
    const float* oddw_v  = (const float*)d_in[2];
    const float* oddw_e  = (const float*)d_in[3];
    const float* w_e_out = (const float*)d_in[4];
    const int*   perma   = (const int*)d_in[5];
    const int*   rc      = (const int*)d_in[6];
    const int*   cr      = (const int*)d_in[7];
    float* out = (float*)d_out;

    const int Bx = in_sizes[0] / (V + 1);
    const int nunits = Bx * P;
    const int npairs = nunits / 2;
    const size_t need = (size_t)nunits * V * sizeof(float);

    if (ws_size >= need) {
        float* eo = (float*)d_ws;
        hipLaunchKernelGGL((bap_kernel<0>), dim3(npairs), dim3(256), 0, stream,
                           x, oddw_v, oddw_e, w_e_out, perma, rc, cr,
                           eo, (const int*)nullptr, (float*)nullptr);
        hipLaunchKernelGGL(out_kernel, dim3(Bx), dim3(256), 0, stream,
                           x, eo, perma, out);
    } else {
        // atomic fallback: needs P*(V+1)*4 = 8KB workspace for inverse perm
        int* invp = (int*)d_ws;
        hipLaunchKernelGGL(inv_kernel, dim3(P), dim3(V + 1), 0, stream, perma, invp);
        hipLaunchKernelGGL(copy_kernel, dim3((out_size + 255) / 256), dim3(256), 0, stream,
                           x, out, out_size);
        hipLaunchKernelGGL((bap_kernel<1>), dim3(npairs), dim3(256), 0, stream,
                           x, oddw_v, oddw_e, w_e_out, perma, rc, cr,
                           (float*)nullptr, invp, out);
    }
}